// Round 13
// baseline (3371.155 us; speedup 1.0000x reference)
//
#include <hip/hip_runtime.h>

typedef short bf16x8 __attribute__((ext_vector_type(8)));
typedef float f32x4  __attribute__((ext_vector_type(4)));
typedef unsigned short u16;
typedef unsigned short u16x8 __attribute__((ext_vector_type(8)));

#define NB   32
#define NS   256
#define NV   32000
#define NE   128
#define NH   128
#define NR   8192   // NB*NS
#define NG   512    // 4*NH
#define NCHUNK 500  // 250 col chunks x 2 wave halves

// DIAGNOSTIC ROUND: in-kernel repeat factors (idempotent recompute)
#define REP_LSTM 8
#define REP_G0   10

__device__ __forceinline__ float sigm(float x){
    return __builtin_amdgcn_rcpf(1.0f + __expf(-x));
}
__device__ __forceinline__ float tanh_fast(float x){
    return 1.0f - 2.0f*__builtin_amdgcn_rcpf(1.0f + __expf(2.0f*x));
}

__device__ __forceinline__ u16 f2bf(float x){
    unsigned u = __float_as_uint(x);
    unsigned r = (u + 0x7FFFu + ((u >> 16) & 1u)) >> 16;
    return (u16)r;
}

// raw barrier: waits only LDS ops, lets global loads/stores stay in flight
__device__ __forceinline__ void lds_barrier(){
    asm volatile("s_waitcnt lgkmcnt(0)" ::: "memory");
    __builtin_amdgcn_s_barrier();
    __builtin_amdgcn_sched_barrier(0);
}

// hh[b][j] = b_ih[j] + b_hh[j] + dot(h0[b,:], W_hh[j,:])
__global__ __launch_bounds__(256) void khh(const float* __restrict__ h0,
                                           const float* __restrict__ W_hh,
                                           const float* __restrict__ b_ih,
                                           const float* __restrict__ b_hh,
                                           float* __restrict__ hh){
    int idx = blockIdx.x*256 + threadIdx.x;      // 0..16383
    int b = idx >> 9, j = idx & 511;
    const float4* h4 = (const float4*)(h0 + b*NH);
    const float4* w4 = (const float4*)(W_hh + j*NH);
    float acc = b_ih[j] + b_hh[j];
    #pragma unroll
    for (int k = 0; k < 32; ++k){
        float4 a = h4[k], w = w4[k];
        acc += a.x*w.x + a.y*w.y + a.z*w.z + a.w*w.w;
    }
    hh[idx] = acc;
}

// W_pred fp32 -> bf16
__global__ __launch_bounds__(256) void kwb(const float* __restrict__ src, u16* __restrict__ dst){
    int i = (blockIdx.x*256 + threadIdx.x)*8;
    float4 a = *(const float4*)(src + i);
    float4 b = *(const float4*)(src + i + 4);
    u16x8 o;
    o[0]=f2bf(a.x); o[1]=f2bf(a.y); o[2]=f2bf(a.z); o[3]=f2bf(a.w);
    o[4]=f2bf(b.x); o[5]=f2bf(b.y); o[6]=f2bf(b.z); o[7]=f2bf(b.w);
    *(u16x8*)(dst + i) = o;
}

// xg[r][j] = dot(emb[seq[r]], W_ih[j][0:128]);  16 rows x 512 cols per block
__global__ __launch_bounds__(256) void kxg(const int* __restrict__ seq,
                                           const float* __restrict__ emb,
                                           const float* __restrict__ W_ih,
                                           float* __restrict__ xg){
    __shared__ float4 xs[16][32];
    int m0 = blockIdx.x * 16;
    int t = threadIdx.x;
    int r = t >> 4, k4 = t & 15;
    int tok = seq[m0 + r];
    xs[r][k4]      = *(const float4*)(emb + (size_t)tok*NE + k4*4);
    xs[r][k4 + 16] = *(const float4*)(emb + (size_t)tok*NE + (k4+16)*4);
    __syncthreads();
    int j0 = t, j1 = t + 256;
    const float4* w0 = (const float4*)(W_ih + (size_t)j0*256);
    const float4* w1 = (const float4*)(W_ih + (size_t)j1*256);
    float acc0[16], acc1[16];
    #pragma unroll
    for (int r2 = 0; r2 < 16; ++r2){ acc0[r2]=0.f; acc1[r2]=0.f; }
    #pragma unroll
    for (int k = 0; k < 32; ++k){
        float4 wa = w0[k], wb = w1[k];
        #pragma unroll
        for (int r2 = 0; r2 < 16; ++r2){
            float4 xv = xs[r2][k];
            acc0[r2] += xv.x*wa.x + xv.y*wa.y + xv.z*wa.z + xv.w*wa.w;
            acc1[r2] += xv.x*wb.x + xv.y*wb.y + xv.z*wb.z + xv.w*wb.w;
        }
    }
    #pragma unroll
    for (int r2 = 0; r2 < 16; ++r2){
        xg[(size_t)(m0+r2)*NG + j0] = acc0[r2];
        xg[(size_t)(m0+r2)*NG + j1] = acc1[r2];
    }
}

// Sequential LSTM, one block/batch, 256 threads, 2 gates/thread, (256,1)
// bounds so the 128 packed weight regs stay in registers.
// DIAGNOSTIC: REP_LSTM in-kernel reps; presence in top-5 <=> spill unfixed.
__global__ __launch_bounds__(256, 1) void klstm(const float* __restrict__ xg,
                                                const float* __restrict__ hh,
                                                const float* __restrict__ W_ih,
                                                const float* __restrict__ c0,
                                                u16* __restrict__ hs){
    __shared__ __align__(16) unsigned hsh2[2][64];   // h as 64 packed bf16 pairs, x2 buffers
    int b = blockIdx.x, t = threadIdx.x;
    int r = t >> 1, odd = t & 1;
    int gA = r + (odd ? 128 : 0);        // i-gate row (even) / f-gate row (odd)
    int gB = gA + 256;                   // g-gate row (even) / o-gate row (odd)
    unsigned w2a[64], w2b[64];
    const float2* wra = (const float2*)(W_ih + (size_t)gA*256 + 128);
    const float2* wrb = (const float2*)(W_ih + (size_t)gB*256 + 128);
    #pragma unroll
    for (int k = 0; k < 64; ++k){
        float2 va = wra[k], vb = wrb[k];
        w2a[k] = ((unsigned)f2bf(va.y) << 16) | (unsigned)f2bf(va.x);
        w2b[k] = ((unsigned)f2bf(vb.y) << 16) | (unsigned)f2bf(vb.x);
    }
    float hba = hh[b*NG + gA];
    float hbb = hh[b*NG + gB];
    float c0r = c0[b*NH + r];
    const float* xrow = xg + (size_t)b*NS*NG;
    u16* hrow = hs + (size_t)b*NS*NH;
    for (int rep = 0; rep < REP_LSTM; ++rep){
        if (t < 64){ hsh2[0][t] = 0u; }      // h_init = 0
        lds_barrier();
        float xva = xrow[gA], xvb = xrow[gB];
        for (int s = 0; s < NS; ++s){
            float xna = 0.f, xnb = 0.f;
            if (s+1 < NS){ xna = xrow[(size_t)(s+1)*NG + gA]; xnb = xrow[(size_t)(s+1)*NG + gB]; }
            float a0=0.f,a1=0.f,a2=0.f,a3=0.f,b0=0.f,b1=0.f,b2=0.f,b3=0.f;
            const uint4* h4 = (const uint4*)&hsh2[s & 1][0];
            #pragma unroll
            for (int k = 0; k < 16; ++k){
                uint4 hv = h4[k];
                asm("v_dot2_f32_bf16 %0, %1, %2, %0" : "+v"(a0) : "v"(hv.x), "v"(w2a[4*k+0]));
                asm("v_dot2_f32_bf16 %0, %1, %2, %0" : "+v"(a1) : "v"(hv.y), "v"(w2a[4*k+1]));
                asm("v_dot2_f32_bf16 %0, %1, %2, %0" : "+v"(a2) : "v"(hv.z), "v"(w2a[4*k+2]));
                asm("v_dot2_f32_bf16 %0, %1, %2, %0" : "+v"(a3) : "v"(hv.w), "v"(w2a[4*k+3]));
                asm("v_dot2_f32_bf16 %0, %1, %2, %0" : "+v"(b0) : "v"(hv.x), "v"(w2b[4*k+0]));
                asm("v_dot2_f32_bf16 %0, %1, %2, %0" : "+v"(b1) : "v"(hv.y), "v"(w2b[4*k+1]));
                asm("v_dot2_f32_bf16 %0, %1, %2, %0" : "+v"(b2) : "v"(hv.z), "v"(w2b[4*k+2]));
                asm("v_dot2_f32_bf16 %0, %1, %2, %0" : "+v"(b3) : "v"(hv.w), "v"(w2b[4*k+3]));
            }
            float gateA = hba + xva + ((a0+a1)+(a2+a3));   // i (even) / f (odd)
            float gateB = hbb + xvb + ((b0+b1)+(b2+b3));   // g (even) / o (odd)
            float fg = __shfl_xor(gateA, 1);               // even lane receives f
            float og = __shfl_xor(gateB, 1);               // even lane receives o
            float cc = sigm(fg)*c0r + sigm(gateA)*tanh_fast(gateB);
            float h  = sigm(og)*tanh_fast(cc);
            u16 hb16 = f2bf(h);
            if (!odd) hrow[s*NH + r] = hb16;
            unsigned hpart = __shfl_xor((unsigned)hb16, 2);  // h[r^1] (valid on even lanes)
            if ((t & 3) == 0) hsh2[(s & 1) ^ 1][r >> 1] = (hpart << 16) | (unsigned)hb16;
            lds_barrier();
            xva = xna; xvb = xnb;
        }
    }
}

// Persistent-column bf16 MFMA GEMM: 500 blocks, 256 threads, tile 128x128,
// 2 blocks/CU. PASS 0: coalesced per-wave psum store (500 partial chunks).
// PASS 1: out = logit - lse[row].
// DIAGNOSTIC: REP in-kernel reps on PASS 0 to surface VGPR/MfmaUtil/VALUBusy.
template<int PASS, int REP>
__global__ __launch_bounds__(256, 2) void kgemm(const u16* __restrict__ hsb,
                                                const u16* __restrict__ wb,
                                                const float* __restrict__ bpred,
                                                const float* __restrict__ lse,
                                                float* __restrict__ psum,
                                                float* __restrict__ out){
    extern __shared__ char smem[];
    u16* Al = (u16*)smem;                 // [128][136] = 34,816 B
    u16* Bl = Al + 128*136;               // [128][136] = 34,816 B
    int tid = threadIdx.x;
    int bid = blockIdx.x;
    int c    = bid >> 1;                  // col chunk 0..249
    int half = bid & 1;                   // row half
    int n0 = c * 128;
    int mbase = half * 4096;

    int wid = tid >> 6, lane = tid & 63;
    int wr = wid >> 1, wc = wid & 1;      // 2 row-groups x 2 col-groups of 64
    int l15 = lane & 15, l4 = lane >> 4;
    const float L2E = 1.44269504f;
    float4 bp4[4], bpl4[4];
    #pragma unroll
    for (int f = 0; f < 4; ++f){
        bp4[f] = *(const float4*)&bpred[n0 + wc*64 + f*16 + l4*4];
        bpl4[f].x = bp4[f].x * L2E; bpl4[f].y = bp4[f].y * L2E;
        bpl4[f].z = bp4[f].z * L2E; bpl4[f].w = bp4[f].w * L2E;
    }

    for (int rep = 0; rep < REP; ++rep){
        __syncthreads();   // protect Al/Bl from previous rep's readers
        uint4 breg[8];
        #pragma unroll
        for (int i = 0; i < 8; ++i){
            int flat = tid + 256*i; int row = flat >> 4, ch = flat & 15;
            breg[i] = *(const uint4*)&wb[(size_t)(n0+row)*NH + ch*8];
        }
        uint4 areg[8];
        #pragma unroll
        for (int i = 0; i < 8; ++i){
            int flat = tid + 256*i; int row = flat >> 4, ch = flat & 15;
            areg[i] = *(const uint4*)&hsb[(size_t)(mbase + row)*NH + ch*8];
        }
        #pragma unroll
        for (int i = 0; i < 8; ++i){
            int flat = tid + 256*i; int row = flat >> 4, ch = flat & 15;
            *(uint4*)&Bl[row*136 + ch*8] = breg[i];
        }
        #pragma unroll
        for (int i = 0; i < 8; ++i){
            int flat = tid + 256*i; int row = flat >> 4, ch = flat & 15;
            *(uint4*)&Al[row*136 + ch*8] = areg[i];
        }
        __syncthreads();

        for (int r = 0; r < 32; ++r){
            if (r + 1 < 32){
                #pragma unroll
                for (int i = 0; i < 8; ++i){
                    int flat = tid + 256*i; int row = flat >> 4, ch = flat & 15;
                    areg[i] = *(const uint4*)&hsb[(size_t)(mbase + (r+1)*128 + row)*NH + ch*8];
                }
            }
            bf16x8 af[4][4];
            #pragma unroll
            for (int q = 0; q < 4; ++q)
                #pragma unroll
                for (int kk = 0; kk < 4; ++kk)
                    af[q][kk] = *(const bf16x8*)&Al[(wr*64 + q*16 + l15)*136 + kk*32 + l4*8];
            f32x4 acc[4][4];
            #pragma unroll
            for (int q = 0; q < 4; ++q)
                #pragma unroll
                for (int f = 0; f < 4; ++f)
                    acc[q][f] = (f32x4){0.f,0.f,0.f,0.f};
            #pragma unroll
            for (int f = 0; f < 4; ++f){
                bf16x8 bfr[4];
                #pragma unroll
                for (int kk = 0; kk < 4; ++kk)
                    bfr[kk] = *(const bf16x8*)&Bl[(wc*64 + f*16 + l15)*136 + kk*32 + l4*8];
                #pragma unroll
                for (int q = 0; q < 4; ++q)
                    #pragma unroll
                    for (int kk = 0; kk < 4; ++kk)
                        acc[q][f] = __builtin_amdgcn_mfma_f32_16x16x32_bf16(bfr[kk], af[q][kk], acc[q][f], 0, 0, 0);
            }

            lds_barrier();
            if (r + 1 < 32){
                #pragma unroll
                for (int i = 0; i < 8; ++i){
                    int flat = tid + 256*i; int row = flat >> 4, ch = flat & 15;
                    *(uint4*)&Al[row*136 + ch*8] = areg[i];
                }
            }

            if (PASS == 0){
                float lsum[4];
                #pragma unroll
                for (int q = 0; q < 4; ++q){
                    float s = 0.f;
                    #pragma unroll
                    for (int f = 0; f < 4; ++f)
                        #pragma unroll
                        for (int rr = 0; rr < 4; ++rr){
                            float tt = fmaf(acc[q][f][rr], L2E, bpl4[f][rr]);
                            float e; asm("v_exp_f32 %0, %1" : "=v"(e) : "v"(tt));
                            s += e;
                        }
                    s += __shfl_xor(s, 16);
                    s += __shfl_xor(s, 32);
                    lsum[q] = s;
                }
                float sv = (l4 == 0) ? lsum[0] : (l4 == 1) ? lsum[1]
                         : (l4 == 2) ? lsum[2] : lsum[3];
                psum[(size_t)(c*2 + wc)*NR + mbase + r*128 + wr*64 + lane] = sv;
            } else {
                #pragma unroll
                for (int q = 0; q < 4; ++q){
                    int grow = mbase + r*128 + wr*64 + q*16 + l15;
                    float lw = lse[grow];
                    float* orow = out + (size_t)grow*NV + n0 + wc*64 + l4*4;
                    #pragma unroll
                    for (int f = 0; f < 4; ++f){
                        f32x4 v;
                        v[0] = acc[q][f][0] + bp4[f].x - lw;
                        v[1] = acc[q][f][1] + bp4[f].y - lw;
                        v[2] = acc[q][f][2] + bp4[f].z - lw;
                        v[3] = acc[q][f][3] + bp4[f].w - lw;
                        *(f32x4*)&orow[f*16] = v;
                    }
                }
            }
            lds_barrier();
        }
    }
}

// lse[row] = log( sum over 500 partial-chunk sums )
__global__ __launch_bounds__(256) void klse(const float* __restrict__ psum,
                                            float* __restrict__ lse){
    int row = blockIdx.x*256 + threadIdx.x;   // 0..8191
    float S = 0.f;
    for (int cc = 0; cc < NCHUNK; ++cc) S += psum[(size_t)cc*NR + row];
    lse[row] = __logf(S);
}

extern "C" void kernel_launch(void* const* d_in, const int* in_sizes, int n_in,
                              void* d_out, int out_size, void* d_ws, size_t ws_size,
                              hipStream_t stream){
    (void)in_sizes; (void)n_in; (void)out_size; (void)ws_size;
    const int*   seq    = (const int*)d_in[0];
    // d_in[1] encoder_output: unused by the reference
    const float* h0     = (const float*)d_in[2];
    const float* c0     = (const float*)d_in[3];
    const float* emb    = (const float*)d_in[4];
    const float* W_ih   = (const float*)d_in[5];
    const float* b_ih   = (const float*)d_in[6];
    const float* W_hh   = (const float*)d_in[7];
    const float* b_hh   = (const float*)d_in[8];
    const float* W_pred = (const float*)d_in[9];
    const float* b_pred = (const float*)d_in[10];
    float* out = (float*)d_out;

    // Workspace layout. psum (500x8192x4 = 16,384,000 B) ALIASES xg.
    char* ws = (char*)d_ws;
    float* xg   = (float*)(ws);               // 16,777,216 B  [0 .. 16.78M)
    float* psum = (float*)(ws);               // 16,384,000 B  (alias xg)
    float* hh   = (float*)(ws + 16777216);    //     65,536 B
    u16*   hsb  = (u16*)  (ws + 16842752);    //  2,097,152 B
    u16*   wbb  = (u16*)  (ws + 18939904);    //  8,192,000 B
    float* lse  = (float*)(ws + 27131904);    //     32,768 B

    khh<<<64, 256, 0, stream>>>(h0, W_hh, b_ih, b_hh, hh);
    kwb<<<2000, 256, 0, stream>>>(W_pred, wbb);
    kxg<<<512, 256, 0, stream>>>(seq, emb, W_ih, xg);
    klstm<<<32, 256, 0, stream>>>(xg, hh, W_ih, c0, hsb);
    kgemm<0, REP_G0><<<500, 256, 69632, stream>>>(hsb, wbb, b_pred, nullptr, psum, out);
    klse<<<32, 256, 0, stream>>>(psum, lse);
    kgemm<1, 1><<<500, 256, 69632, stream>>>(hsb, wbb, b_pred, lse, psum, out);
}

// Round 14
// 715.428 us; speedup vs baseline: 4.7121x; 4.7121x over previous
//
#include <hip/hip_runtime.h>

typedef short bf16x8 __attribute__((ext_vector_type(8)));
typedef float f32x4  __attribute__((ext_vector_type(4)));
typedef unsigned short u16;
typedef unsigned short u16x8 __attribute__((ext_vector_type(8)));

#define NB   32
#define NS   256
#define NV   32000
#define NE   128
#define NH   128
#define NR   8192   // NB*NS
#define NG   512    // 4*NH
#define NCHUNK 500  // 250 col chunks x 2 wave halves

__device__ __forceinline__ float sigm(float x){
    return __builtin_amdgcn_rcpf(1.0f + __expf(-x));
}
__device__ __forceinline__ float tanh_fast(float x){
    return 1.0f - 2.0f*__builtin_amdgcn_rcpf(1.0f + __expf(2.0f*x));
}

__device__ __forceinline__ u16 f2bf(float x){
    unsigned u = __float_as_uint(x);
    unsigned r = (u + 0x7FFFu + ((u >> 16) & 1u)) >> 16;
    return (u16)r;
}

// raw barrier: waits only LDS ops, lets global loads/stores stay in flight
__device__ __forceinline__ void lds_barrier(){
    asm volatile("s_waitcnt lgkmcnt(0)" ::: "memory");
    __builtin_amdgcn_s_barrier();
    __builtin_amdgcn_sched_barrier(0);
}

// hh[b][j] = b_ih[j] + b_hh[j] + dot(h0[b,:], W_hh[j,:])
__global__ __launch_bounds__(256) void khh(const float* __restrict__ h0,
                                           const float* __restrict__ W_hh,
                                           const float* __restrict__ b_ih,
                                           const float* __restrict__ b_hh,
                                           float* __restrict__ hh){
    int idx = blockIdx.x*256 + threadIdx.x;      // 0..16383
    int b = idx >> 9, j = idx & 511;
    const float4* h4 = (const float4*)(h0 + b*NH);
    const float4* w4 = (const float4*)(W_hh + j*NH);
    float acc = b_ih[j] + b_hh[j];
    #pragma unroll
    for (int k = 0; k < 32; ++k){
        float4 a = h4[k], w = w4[k];
        acc += a.x*w.x + a.y*w.y + a.z*w.z + a.w*w.w;
    }
    hh[idx] = acc;
}

// W_pred fp32 -> bf16
__global__ __launch_bounds__(256) void kwb(const float* __restrict__ src, u16* __restrict__ dst){
    int i = (blockIdx.x*256 + threadIdx.x)*8;
    float4 a = *(const float4*)(src + i);
    float4 b = *(const float4*)(src + i + 4);
    u16x8 o;
    o[0]=f2bf(a.x); o[1]=f2bf(a.y); o[2]=f2bf(a.z); o[3]=f2bf(a.w);
    o[4]=f2bf(b.x); o[5]=f2bf(b.y); o[6]=f2bf(b.z); o[7]=f2bf(b.w);
    *(u16x8*)(dst + i) = o;
}

// xg[r][j] = dot(emb[seq[r]], W_ih[j][0:128]);  16 rows x 512 cols per block
__global__ __launch_bounds__(256) void kxg(const int* __restrict__ seq,
                                           const float* __restrict__ emb,
                                           const float* __restrict__ W_ih,
                                           float* __restrict__ xg){
    __shared__ float4 xs[16][32];
    int m0 = blockIdx.x * 16;
    int t = threadIdx.x;
    int r = t >> 4, k4 = t & 15;
    int tok = seq[m0 + r];
    xs[r][k4]      = *(const float4*)(emb + (size_t)tok*NE + k4*4);
    xs[r][k4 + 16] = *(const float4*)(emb + (size_t)tok*NE + (k4+16)*4);
    __syncthreads();
    int j0 = t, j1 = t + 256;
    const float4* w0 = (const float4*)(W_ih + (size_t)j0*256);
    const float4* w1 = (const float4*)(W_ih + (size_t)j1*256);
    float acc0[16], acc1[16];
    #pragma unroll
    for (int r2 = 0; r2 < 16; ++r2){ acc0[r2]=0.f; acc1[r2]=0.f; }
    #pragma unroll
    for (int k = 0; k < 32; ++k){
        float4 wa = w0[k], wb = w1[k];
        #pragma unroll
        for (int r2 = 0; r2 < 16; ++r2){
            float4 xv = xs[r2][k];
            acc0[r2] += xv.x*wa.x + xv.y*wa.y + xv.z*wa.z + xv.w*wa.w;
            acc1[r2] += xv.x*wb.x + xv.y*wb.y + xv.z*wb.z + xv.w*wb.w;
        }
    }
    #pragma unroll
    for (int r2 = 0; r2 < 16; ++r2){
        xg[(size_t)(m0+r2)*NG + j0] = acc0[r2];
        xg[(size_t)(m0+r2)*NG + j1] = acc1[r2];
    }
}

// Sequential LSTM, one block/batch, 256 threads, 2 gates/thread, (256,1).
__global__ __launch_bounds__(256, 1) void klstm(const float* __restrict__ xg,
                                                const float* __restrict__ hh,
                                                const float* __restrict__ W_ih,
                                                const float* __restrict__ c0,
                                                u16* __restrict__ hs){
    __shared__ __align__(16) unsigned hsh2[2][64];   // h as 64 packed bf16 pairs, x2 buffers
    int b = blockIdx.x, t = threadIdx.x;
    int r = t >> 1, odd = t & 1;
    int gA = r + (odd ? 128 : 0);        // i-gate row (even) / f-gate row (odd)
    int gB = gA + 256;                   // g-gate row (even) / o-gate row (odd)
    unsigned w2a[64], w2b[64];
    const float2* wra = (const float2*)(W_ih + (size_t)gA*256 + 128);
    const float2* wrb = (const float2*)(W_ih + (size_t)gB*256 + 128);
    #pragma unroll
    for (int k = 0; k < 64; ++k){
        float2 va = wra[k], vb = wrb[k];
        w2a[k] = ((unsigned)f2bf(va.y) << 16) | (unsigned)f2bf(va.x);
        w2b[k] = ((unsigned)f2bf(vb.y) << 16) | (unsigned)f2bf(vb.x);
    }
    float hba = hh[b*NG + gA];
    float hbb = hh[b*NG + gB];
    float c0r = c0[b*NH + r];
    if (t < 64){ hsh2[0][t] = 0u; }      // h_init = 0
    __syncthreads();
    const float* xrow = xg + (size_t)b*NS*NG;
    u16* hrow = hs + (size_t)b*NS*NH;
    float xva = xrow[gA], xvb = xrow[gB];
    for (int s = 0; s < NS; ++s){
        float xna = 0.f, xnb = 0.f;
        if (s+1 < NS){ xna = xrow[(size_t)(s+1)*NG + gA]; xnb = xrow[(size_t)(s+1)*NG + gB]; }
        float a0=0.f,a1=0.f,a2=0.f,a3=0.f,b0=0.f,b1=0.f,b2=0.f,b3=0.f;
        const uint4* h4 = (const uint4*)&hsh2[s & 1][0];
        #pragma unroll
        for (int k = 0; k < 16; ++k){
            uint4 hv = h4[k];
            asm("v_dot2_f32_bf16 %0, %1, %2, %0" : "+v"(a0) : "v"(hv.x), "v"(w2a[4*k+0]));
            asm("v_dot2_f32_bf16 %0, %1, %2, %0" : "+v"(a1) : "v"(hv.y), "v"(w2a[4*k+1]));
            asm("v_dot2_f32_bf16 %0, %1, %2, %0" : "+v"(a2) : "v"(hv.z), "v"(w2a[4*k+2]));
            asm("v_dot2_f32_bf16 %0, %1, %2, %0" : "+v"(a3) : "v"(hv.w), "v"(w2a[4*k+3]));
            asm("v_dot2_f32_bf16 %0, %1, %2, %0" : "+v"(b0) : "v"(hv.x), "v"(w2b[4*k+0]));
            asm("v_dot2_f32_bf16 %0, %1, %2, %0" : "+v"(b1) : "v"(hv.y), "v"(w2b[4*k+1]));
            asm("v_dot2_f32_bf16 %0, %1, %2, %0" : "+v"(b2) : "v"(hv.z), "v"(w2b[4*k+2]));
            asm("v_dot2_f32_bf16 %0, %1, %2, %0" : "+v"(b3) : "v"(hv.w), "v"(w2b[4*k+3]));
        }
        float gateA = hba + xva + ((a0+a1)+(a2+a3));   // i (even) / f (odd)
        float gateB = hbb + xvb + ((b0+b1)+(b2+b3));   // g (even) / o (odd)
        float fg = __shfl_xor(gateA, 1);               // even lane receives f
        float og = __shfl_xor(gateB, 1);               // even lane receives o
        float cc = sigm(fg)*c0r + sigm(gateA)*tanh_fast(gateB);
        float h  = sigm(og)*tanh_fast(cc);
        u16 hb16 = f2bf(h);
        if (!odd) hrow[s*NH + r] = hb16;
        unsigned hpart = __shfl_xor((unsigned)hb16, 2);  // h[r^1] (valid on even lanes)
        if ((t & 3) == 0) hsh2[(s & 1) ^ 1][r >> 1] = (hpart << 16) | (unsigned)hb16;
        lds_barrier();
        xva = xna; xvb = xnb;
    }
}

// ---------------------------------------------------------------------------
// Barrier-free, LDS-free MFMA GEMM (R13 diagnosis: old version was LDS-pipe +
// barrier bound — MfmaUtil 16.7%, 8.2e7 bank conflicts, both pipes <23%).
// B (W chunk, K=128) is INVARIANT across row tiles -> entire B fragment set
// lives in 64 VGPRs, loaded once from global. A fragments are loaded per-tile
// DIRECTLY global->VGPR (hsb is 2 MB, L2-resident), double-buffered afA/afB
// with a hand-unrolled r+=2 loop (all register indices compile-time).
// Zero LDS, zero barriers, zero bank conflicts; waves fully independent.
// Fragment mapping (validated since R5):
//   af[q][kk]  = hs[(m0 + q*16 + l15)*128 + kk*32 + l4*8 ..+8]
//   bfr[f][kk] = W [(n0 + f*16 + l15)*128 + kk*32 + l4*8 ..+8]
//   acc[q][f]  = mfma(bfr[f][kk], af[q][kk], acc[q][f])
//   acc[q][f][rr] = logit[m0 + q*16 + l15][n0 + f*16 + l4*4 + rr]
// PASS 0: psum[(c*2+wc)][row] = sum_j exp(logit) (coalesced per-wave store).
// PASS 1: out = logit - lse[row].
// ---------------------------------------------------------------------------

#define LOAD_A(DST, R)                                                          \
    _Pragma("unroll")                                                           \
    for (int q = 0; q < 4; ++q){                                                \
        _Pragma("unroll")                                                       \
        for (int kk = 0; kk < 4; ++kk)                                          \
            DST[q][kk] = *(const bf16x8*)&hsb[(size_t)(mbase + (R)*128 + wr*64  \
                         + q*16 + l15)*NH + kk*32 + l4*8];                      \
    }

#define DO_TILE(AF, R)                                                          \
    {                                                                           \
        f32x4 acc[4][4];                                                        \
        _Pragma("unroll")                                                       \
        for (int q = 0; q < 4; ++q)                                             \
            _Pragma("unroll")                                                   \
            for (int f = 0; f < 4; ++f)                                         \
                acc[q][f] = (f32x4){0.f,0.f,0.f,0.f};                           \
        _Pragma("unroll")                                                       \
        for (int f = 0; f < 4; ++f)                                             \
            _Pragma("unroll")                                                   \
            for (int q = 0; q < 4; ++q)                                         \
                _Pragma("unroll")                                               \
                for (int kk = 0; kk < 4; ++kk)                                  \
                    acc[q][f] = __builtin_amdgcn_mfma_f32_16x16x32_bf16(        \
                        bfr[f][kk], AF[q][kk], acc[q][f], 0, 0, 0);             \
        if (PASS == 0){                                                         \
            float lsum[4];                                                      \
            _Pragma("unroll")                                                   \
            for (int q = 0; q < 4; ++q){                                        \
                float s = 0.f;                                                  \
                _Pragma("unroll")                                               \
                for (int f = 0; f < 4; ++f)                                     \
                    _Pragma("unroll")                                           \
                    for (int rr = 0; rr < 4; ++rr){                             \
                        float tt = fmaf(acc[q][f][rr], L2E, bpl4[f][rr]);       \
                        float e; asm("v_exp_f32 %0, %1" : "=v"(e) : "v"(tt));   \
                        s += e;                                                 \
                    }                                                           \
                s += __shfl_xor(s, 16);                                         \
                s += __shfl_xor(s, 32);                                         \
                lsum[q] = s;                                                    \
            }                                                                   \
            float sv = (l4 == 0) ? lsum[0] : (l4 == 1) ? lsum[1]                \
                     : (l4 == 2) ? lsum[2] : lsum[3];                           \
            psum[(size_t)(c*2 + wc)*NR + mbase + (R)*128 + wr*64 + lane] = sv;  \
        } else {                                                                \
            _Pragma("unroll")                                                   \
            for (int q = 0; q < 4; ++q){                                        \
                int grow = mbase + (R)*128 + wr*64 + q*16 + l15;                \
                float lw = lse[grow];                                           \
                float* orow = out + (size_t)grow*NV + n0 + wc*64 + l4*4;        \
                _Pragma("unroll")                                               \
                for (int f = 0; f < 4; ++f){                                    \
                    f32x4 v;                                                    \
                    v[0] = acc[q][f][0] + bp4[f].x - lw;                        \
                    v[1] = acc[q][f][1] + bp4[f].y - lw;                        \
                    v[2] = acc[q][f][2] + bp4[f].z - lw;                        \
                    v[3] = acc[q][f][3] + bp4[f].w - lw;                        \
                    *(f32x4*)&orow[f*16] = v;                                   \
                }                                                               \
            }                                                                   \
        }                                                                       \
    }

template<int PASS>
__global__ __launch_bounds__(256, 2) void kgemm(const u16* __restrict__ hsb,
                                                const u16* __restrict__ wb,
                                                const float* __restrict__ bpred,
                                                const float* __restrict__ lse,
                                                float* __restrict__ psum,
                                                float* __restrict__ out){
    int tid = threadIdx.x;
    int bid = blockIdx.x;
    int c    = bid >> 1;                  // col chunk 0..249
    int half = bid & 1;                   // row half
    int n0 = c * 128;
    int mbase = half * 4096;

    int wid = tid >> 6, lane = tid & 63;
    int wr = wid >> 1, wc = wid & 1;      // 2 row-groups x 2 col-groups of 64
    int l15 = lane & 15, l4 = lane >> 4;
    const float L2E = 1.44269504f;
    float4 bp4[4], bpl4[4];
    #pragma unroll
    for (int f = 0; f < 4; ++f){
        bp4[f] = *(const float4*)&bpred[n0 + wc*64 + f*16 + l4*4];
        bpl4[f].x = bp4[f].x * L2E; bpl4[f].y = bp4[f].y * L2E;
        bpl4[f].z = bp4[f].z * L2E; bpl4[f].w = bp4[f].w * L2E;
    }

    // B fragments: entire 128x128 W chunk for this wave's col group, in regs.
    bf16x8 bfr[4][4];
    #pragma unroll
    for (int f = 0; f < 4; ++f)
        #pragma unroll
        for (int kk = 0; kk < 4; ++kk)
            bfr[f][kk] = *(const bf16x8*)&wb[(size_t)(n0 + wc*64 + f*16 + l15)*NH + kk*32 + l4*8];

    bf16x8 afA[4][4], afB[4][4];
    LOAD_A(afA, 0);
    for (int r = 0; r < 32; r += 2){
        LOAD_A(afB, r+1);
        DO_TILE(afA, r);
        if (r + 2 < 32) LOAD_A(afA, r+2);
        DO_TILE(afB, r+1);
    }
}

// lse[row] = log( sum over 500 partial-chunk sums )   (max-free: logits bounded)
__global__ __launch_bounds__(256) void klse(const float* __restrict__ psum,
                                            float* __restrict__ lse){
    int row = blockIdx.x*256 + threadIdx.x;   // 0..8191
    float S = 0.f;
    for (int cc = 0; cc < NCHUNK; ++cc) S += psum[(size_t)cc*NR + row];
    lse[row] = __logf(S);
}

extern "C" void kernel_launch(void* const* d_in, const int* in_sizes, int n_in,
                              void* d_out, int out_size, void* d_ws, size_t ws_size,
                              hipStream_t stream){
    (void)in_sizes; (void)n_in; (void)out_size; (void)ws_size;
    const int*   seq    = (const int*)d_in[0];
    // d_in[1] encoder_output: unused by the reference
    const float* h0     = (const float*)d_in[2];
    const float* c0     = (const float*)d_in[3];
    const float* emb    = (const float*)d_in[4];
    const float* W_ih   = (const float*)d_in[5];
    const float* b_ih   = (const float*)d_in[6];
    const float* W_hh   = (const float*)d_in[7];
    const float* b_hh   = (const float*)d_in[8];
    const float* W_pred = (const float*)d_in[9];
    const float* b_pred = (const float*)d_in[10];
    float* out = (float*)d_out;

    // Workspace layout. psum (500x8192x4 = 16,384,000 B) ALIASES xg.
    char* ws = (char*)d_ws;
    float* xg   = (float*)(ws);               // 16,777,216 B  [0 .. 16.78M)
    float* psum = (float*)(ws);               // 16,384,000 B  (alias xg)
    float* hh   = (float*)(ws + 16777216);    //     65,536 B
    u16*   hsb  = (u16*)  (ws + 16842752);    //  2,097,152 B
    u16*   wbb  = (u16*)  (ws + 18939904);    //  8,192,000 B
    float* lse  = (float*)(ws + 27131904);    //     32,768 B

    khh<<<64, 256, 0, stream>>>(h0, W_hh, b_ih, b_hh, hh);
    kwb<<<2000, 256, 0, stream>>>(W_pred, wbb);
    kxg<<<512, 256, 0, stream>>>(seq, emb, W_ih, xg);
    klstm<<<32, 256, 0, stream>>>(xg, hh, W_ih, c0, hsb);
    kgemm<0><<<500, 256, 0, stream>>>(hsb, wbb, b_pred, nullptr, psum, out);
    klse<<<32, 256, 0, stream>>>(psum, lse);
    kgemm<1><<<500, 256, 0, stream>>>(hsb, wbb, b_pred, lse, psum, out);
}

// Round 15
// 558.915 us; speedup vs baseline: 6.0316x; 1.2800x over previous
//
#include <hip/hip_runtime.h>

typedef short bf16x8 __attribute__((ext_vector_type(8)));
typedef float f32x4  __attribute__((ext_vector_type(4)));
typedef unsigned short u16;
typedef unsigned short u16x8 __attribute__((ext_vector_type(8)));

#define NB   32
#define NS   256
#define NV   32000
#define NE   128
#define NH   128
#define NR   8192   // NB*NS
#define NG   512    // 4*NH
#define NCHUNK 500  // 250 col chunks x 2 wave halves

__device__ __forceinline__ float sigm(float x){
    return __builtin_amdgcn_rcpf(1.0f + __expf(-x));
}
__device__ __forceinline__ float tanh_fast(float x){
    return 1.0f - 2.0f*__builtin_amdgcn_rcpf(1.0f + __expf(2.0f*x));
}

__device__ __forceinline__ u16 f2bf(float x){
    unsigned u = __float_as_uint(x);
    unsigned r = (u + 0x7FFFu + ((u >> 16) & 1u)) >> 16;
    return (u16)r;
}

// raw barrier: waits only LDS ops, lets global loads/stores stay in flight
__device__ __forceinline__ void lds_barrier(){
    asm volatile("s_waitcnt lgkmcnt(0)" ::: "memory");
    __builtin_amdgcn_s_barrier();
    __builtin_amdgcn_sched_barrier(0);
}

// ---------------------------------------------------------------------------
// Fragment-major (F) layout for a [R][128] bf16 matrix, shared by A and B:
//   row m = rb*64 + q*16 + l15,  col j = kk*32 + l4*8 + e,  lane = l4*16+l15
//   F-addr = rb*8192 + (kk*4+q)*512 + lane*8 + e      (u16 units)
// A wave's fragment load then reads 64 consecutive 16B chunks per
// instruction (1KB, perfectly coalesced), single base + const offsets.
// ---------------------------------------------------------------------------

// hh[b][j] = b_ih[j] + b_hh[j] + dot(h0[b,:], W_hh[j,:])
__global__ __launch_bounds__(256) void khh(const float* __restrict__ h0,
                                           const float* __restrict__ W_hh,
                                           const float* __restrict__ b_ih,
                                           const float* __restrict__ b_hh,
                                           float* __restrict__ hh){
    int idx = blockIdx.x*256 + threadIdx.x;      // 0..16383
    int b = idx >> 9, j = idx & 511;
    const float4* h4 = (const float4*)(h0 + b*NH);
    const float4* w4 = (const float4*)(W_hh + j*NH);
    float acc = b_ih[j] + b_hh[j];
    #pragma unroll
    for (int k = 0; k < 32; ++k){
        float4 a = h4[k], w = w4[k];
        acc += a.x*w.x + a.y*w.y + a.z*w.z + a.w*w.w;
    }
    hh[idx] = acc;
}

// W_pred fp32 -> bf16, written directly in F layout (write-coalesced;
// reads are 32B at 256B stride, ~2x over-read of an HBM stream, cheap).
__global__ __launch_bounds__(256) void kwb(const float* __restrict__ src, u16* __restrict__ dst){
    int a8 = blockIdx.x*256 + threadIdx.x;    // 512000 16B-chunks
    int a = a8 * 8;
    int rb = a >> 13; int blk = (a >> 9) & 15; int lane = (a >> 3) & 63;
    int q = blk & 3, kk = blk >> 2;
    int l15 = lane & 15, l4 = lane >> 4;
    int m = rb*64 + q*16 + l15;
    int j = kk*32 + l4*8;
    const float* s = src + (size_t)m*NH + j;
    float4 x = *(const float4*)s, y = *(const float4*)(s + 4);
    u16x8 o;
    o[0]=f2bf(x.x); o[1]=f2bf(x.y); o[2]=f2bf(x.z); o[3]=f2bf(x.w);
    o[4]=f2bf(y.x); o[5]=f2bf(y.y); o[6]=f2bf(y.z); o[7]=f2bf(y.w);
    *(u16x8*)&dst[a] = o;
}

// hsb (row-major [8192][128] bf16) -> hsbF (F layout). 2 MB, L2-resident.
__global__ __launch_bounds__(256) void ktr(const u16* __restrict__ src, u16* __restrict__ dst){
    int a8 = blockIdx.x*256 + threadIdx.x;    // 262144 16B-chunks
    int a = a8 * 8;
    int rb = a >> 13; int blk = (a >> 9) & 15; int lane = (a >> 3) & 63;
    int q = blk & 3, kk = blk >> 2;
    int l15 = lane & 15, l4 = lane >> 4;
    int m = rb*64 + q*16 + l15;
    int j = kk*32 + l4*8;
    *(uint4*)&dst[a] = *(const uint4*)&src[(size_t)m*NH + j];
}

// xg[r][j] = dot(emb[seq[r]], W_ih[j][0:128]);  16 rows x 512 cols per block
__global__ __launch_bounds__(256) void kxg(const int* __restrict__ seq,
                                           const float* __restrict__ emb,
                                           const float* __restrict__ W_ih,
                                           float* __restrict__ xg){
    __shared__ float4 xs[16][32];
    int m0 = blockIdx.x * 16;
    int t = threadIdx.x;
    int r = t >> 4, k4 = t & 15;
    int tok = seq[m0 + r];
    xs[r][k4]      = *(const float4*)(emb + (size_t)tok*NE + k4*4);
    xs[r][k4 + 16] = *(const float4*)(emb + (size_t)tok*NE + (k4+16)*4);
    __syncthreads();
    int j0 = t, j1 = t + 256;
    const float4* w0 = (const float4*)(W_ih + (size_t)j0*256);
    const float4* w1 = (const float4*)(W_ih + (size_t)j1*256);
    float acc0[16], acc1[16];
    #pragma unroll
    for (int r2 = 0; r2 < 16; ++r2){ acc0[r2]=0.f; acc1[r2]=0.f; }
    #pragma unroll
    for (int k = 0; k < 32; ++k){
        float4 wa = w0[k], wb = w1[k];
        #pragma unroll
        for (int r2 = 0; r2 < 16; ++r2){
            float4 xv = xs[r2][k];
            acc0[r2] += xv.x*wa.x + xv.y*wa.y + xv.z*wa.z + xv.w*wa.w;
            acc1[r2] += xv.x*wb.x + xv.y*wb.y + xv.z*wb.z + xv.w*wb.w;
        }
    }
    #pragma unroll
    for (int r2 = 0; r2 < 16; ++r2){
        xg[(size_t)(m0+r2)*NG + j0] = acc0[r2];
        xg[(size_t)(m0+r2)*NG + j1] = acc1[r2];
    }
}

// Sequential LSTM, one block/batch, 256 threads, 2 gates/thread, (256,1).
// x-prefetch deepened to 4 steps (xg is 16MB -> HBM latency ~900cyc; the
// old 1-step lookahead (~350cyc) stalled every step). Group-of-4 unroll
// with NAMED registers (runtime-indexed arrays would spill — rule #20).
#define LSTM_STEP(S, XA, XB) {                                                  \
    float a0=0.f,a1=0.f,a2=0.f,a3=0.f,b0=0.f,b1=0.f,b2=0.f,b3=0.f;              \
    const uint4* h4 = (const uint4*)&hsh2[(S) & 1][0];                          \
    _Pragma("unroll")                                                           \
    for (int k = 0; k < 16; ++k){                                               \
        uint4 hv = h4[k];                                                       \
        asm("v_dot2_f32_bf16 %0, %1, %2, %0" : "+v"(a0) : "v"(hv.x), "v"(w2a[4*k+0])); \
        asm("v_dot2_f32_bf16 %0, %1, %2, %0" : "+v"(a1) : "v"(hv.y), "v"(w2a[4*k+1])); \
        asm("v_dot2_f32_bf16 %0, %1, %2, %0" : "+v"(a2) : "v"(hv.z), "v"(w2a[4*k+2])); \
        asm("v_dot2_f32_bf16 %0, %1, %2, %0" : "+v"(a3) : "v"(hv.w), "v"(w2a[4*k+3])); \
        asm("v_dot2_f32_bf16 %0, %1, %2, %0" : "+v"(b0) : "v"(hv.x), "v"(w2b[4*k+0])); \
        asm("v_dot2_f32_bf16 %0, %1, %2, %0" : "+v"(b1) : "v"(hv.y), "v"(w2b[4*k+1])); \
        asm("v_dot2_f32_bf16 %0, %1, %2, %0" : "+v"(b2) : "v"(hv.z), "v"(w2b[4*k+2])); \
        asm("v_dot2_f32_bf16 %0, %1, %2, %0" : "+v"(b3) : "v"(hv.w), "v"(w2b[4*k+3])); \
    }                                                                           \
    float gateA = hba + (XA) + ((a0+a1)+(a2+a3));                               \
    float gateB = hbb + (XB) + ((b0+b1)+(b2+b3));                               \
    float fg = __shfl_xor(gateA, 1);                                            \
    float og = __shfl_xor(gateB, 1);                                            \
    float cc = sigm(fg)*c0r + sigm(gateA)*tanh_fast(gateB);                     \
    float h  = sigm(og)*tanh_fast(cc);                                          \
    u16 hb16 = f2bf(h);                                                         \
    if (!odd) hrow[(S)*NH + r] = hb16;                                          \
    unsigned hpart = __shfl_xor((unsigned)hb16, 2);                             \
    if ((t & 3) == 0) hsh2[((S) & 1) ^ 1][r >> 1] = (hpart << 16) | (unsigned)hb16; \
    lds_barrier();                                                              \
}

__global__ __launch_bounds__(256, 1) void klstm(const float* __restrict__ xg,
                                                const float* __restrict__ hh,
                                                const float* __restrict__ W_ih,
                                                const float* __restrict__ c0,
                                                u16* __restrict__ hs){
    __shared__ __align__(16) unsigned hsh2[2][64];   // h as 64 packed bf16 pairs, x2 buffers
    int b = blockIdx.x, t = threadIdx.x;
    int r = t >> 1, odd = t & 1;
    int gA = r + (odd ? 128 : 0);        // i-gate row (even) / f-gate row (odd)
    int gB = gA + 256;                   // g-gate row (even) / o-gate row (odd)
    unsigned w2a[64], w2b[64];
    const float2* wra = (const float2*)(W_ih + (size_t)gA*256 + 128);
    const float2* wrb = (const float2*)(W_ih + (size_t)gB*256 + 128);
    #pragma unroll
    for (int k = 0; k < 64; ++k){
        float2 va = wra[k], vb = wrb[k];
        w2a[k] = ((unsigned)f2bf(va.y) << 16) | (unsigned)f2bf(va.x);
        w2b[k] = ((unsigned)f2bf(vb.y) << 16) | (unsigned)f2bf(vb.x);
    }
    float hba = hh[b*NG + gA];
    float hbb = hh[b*NG + gB];
    float c0r = c0[b*NH + r];
    if (t < 64){ hsh2[0][t] = 0u; }      // h_init = 0
    __syncthreads();
    const float* xrow = xg + (size_t)b*NS*NG;
    u16* hrow = hs + (size_t)b*NS*NH;
    float x0a = xrow[gA],        x0b = xrow[gB];
    float x1a = xrow[NG+gA],     x1b = xrow[NG+gB];
    float x2a = xrow[2*NG+gA],   x2b = xrow[2*NG+gB];
    float x3a = xrow[3*NG+gA],   x3b = xrow[3*NG+gB];
    for (int s4 = 0; s4 < NS; s4 += 4){
        float n0a=0.f,n0b=0.f,n1a=0.f,n1b=0.f,n2a=0.f,n2b=0.f,n3a=0.f,n3b=0.f;
        if (s4 + 4 < NS){
            const float* xn = xrow + (size_t)(s4+4)*NG;
            n0a = xn[gA];      n0b = xn[gB];
            n1a = xn[NG+gA];   n1b = xn[NG+gB];
            n2a = xn[2*NG+gA]; n2b = xn[2*NG+gB];
            n3a = xn[3*NG+gA]; n3b = xn[3*NG+gB];
        }
        LSTM_STEP(s4+0, x0a, x0b);
        LSTM_STEP(s4+1, x1a, x1b);
        LSTM_STEP(s4+2, x2a, x2b);
        LSTM_STEP(s4+3, x3a, x3b);
        x0a=n0a; x0b=n0b; x1a=n1a; x1b=n1b;
        x2a=n2a; x2b=n2b; x3a=n3a; x3b=n3b;
    }
}

// ---------------------------------------------------------------------------
// Barrier-free, LDS-free MFMA GEMM with COALESCED F-layout fragment loads
// (R14 regression diagnosis: direct row-major fragment loads were 16B/lane
// at 256B stride -> 64 cache lines per instruction, VMEM-pipe bound).
// B frags (64 VGPR) loaded once; A frags loaded per-tile, double-buffered.
// PASS 0: psum[(c*2+wc)][row] = sum_j exp(logit) (coalesced per-wave store).
// PASS 1: out = logit - lse[row].
// ---------------------------------------------------------------------------

#define LOAD_A(DST, R) {                                                        \
    int rbA = (mbase >> 6) + (R)*2 + wr;                                        \
    const u16* pa = hsbF + (size_t)rbA*8192 + lane*8;                           \
    _Pragma("unroll")                                                           \
    for (int q = 0; q < 4; ++q)                                                 \
        _Pragma("unroll")                                                       \
        for (int kk = 0; kk < 4; ++kk)                                          \
            DST[q][kk] = *(const bf16x8*)&pa[(kk*4 + q)*512];                   \
}

#define DO_TILE(AF, R)                                                          \
    {                                                                           \
        f32x4 acc[4][4];                                                        \
        _Pragma("unroll")                                                       \
        for (int q = 0; q < 4; ++q)                                             \
            _Pragma("unroll")                                                   \
            for (int f = 0; f < 4; ++f)                                         \
                acc[q][f] = (f32x4){0.f,0.f,0.f,0.f};                           \
        _Pragma("unroll")                                                       \
        for (int f = 0; f < 4; ++f)                                             \
            _Pragma("unroll")                                                   \
            for (int q = 0; q < 4; ++q)                                         \
                _Pragma("unroll")                                               \
                for (int kk = 0; kk < 4; ++kk)                                  \
                    acc[q][f] = __builtin_amdgcn_mfma_f32_16x16x32_bf16(        \
                        bfr[f][kk], AF[q][kk], acc[q][f], 0, 0, 0);             \
        if (PASS == 0){                                                         \
            float lsum[4];                                                      \
            _Pragma("unroll")                                                   \
            for (int q = 0; q < 4; ++q){                                        \
                float s = 0.f;                                                  \
                _Pragma("unroll")                                               \
                for (int f = 0; f < 4; ++f)                                     \
                    _Pragma("unroll")                                           \
                    for (int rr = 0; rr < 4; ++rr){                             \
                        float tt = fmaf(acc[q][f][rr], L2E, bpl4[f][rr]);       \
                        float e; asm("v_exp_f32 %0, %1" : "=v"(e) : "v"(tt));   \
                        s += e;                                                 \
                    }                                                           \
                s += __shfl_xor(s, 16);                                         \
                s += __shfl_xor(s, 32);                                         \
                lsum[q] = s;                                                    \
            }                                                                   \
            float sv = (l4 == 0) ? lsum[0] : (l4 == 1) ? lsum[1]                \
                     : (l4 == 2) ? lsum[2] : lsum[3];                           \
            psum[(size_t)(c*2 + wc)*NR + mbase + (R)*128 + wr*64 + lane] = sv;  \
        } else {                                                                \
            _Pragma("unroll")                                                   \
            for (int q = 0; q < 4; ++q){                                        \
                int grow = mbase + (R)*128 + wr*64 + q*16 + l15;                \
                float lw = lse[grow];                                           \
                float* orow = out + (size_t)grow*NV + n0 + wc*64 + l4*4;        \
                _Pragma("unroll")                                               \
                for (int f = 0; f < 4; ++f){                                    \
                    f32x4 v;                                                    \
                    v[0] = acc[q][f][0] + bp4[f].x - lw;                        \
                    v[1] = acc[q][f][1] + bp4[f].y - lw;                        \
                    v[2] = acc[q][f][2] + bp4[f].z - lw;                        \
                    v[3] = acc[q][f][3] + bp4[f].w - lw;                        \
                    *(f32x4*)&orow[f*16] = v;                                   \
                }                                                               \
            }                                                                   \
        }                                                                       \
    }

template<int PASS>
__global__ __launch_bounds__(256, 2) void kgemm(const u16* __restrict__ hsbF,
                                                const u16* __restrict__ wbF,
                                                const float* __restrict__ bpred,
                                                const float* __restrict__ lse,
                                                float* __restrict__ psum,
                                                float* __restrict__ out){
    int tid = threadIdx.x;
    int bid = blockIdx.x;
    int c    = bid >> 1;                  // col chunk 0..249
    int half = bid & 1;                   // row half
    int n0 = c * 128;
    int mbase = half * 4096;

    int wid = tid >> 6, lane = tid & 63;
    int wr = wid >> 1, wc = wid & 1;      // 2 row-groups x 2 col-groups of 64
    int l15 = lane & 15, l4 = lane >> 4;
    const float L2E = 1.44269504f;
    float4 bp4[4], bpl4[4];
    #pragma unroll
    for (int f = 0; f < 4; ++f){
        bp4[f] = *(const float4*)&bpred[n0 + wc*64 + f*16 + l4*4];
        bpl4[f].x = bp4[f].x * L2E; bpl4[f].y = bp4[f].y * L2E;
        bpl4[f].z = bp4[f].z * L2E; bpl4[f].w = bp4[f].w * L2E;
    }

    // B fragments: this wave's 64x128 W chunk, in regs, coalesced F reads.
    bf16x8 bfr[4][4];
    {
        int rbB = c*2 + wc;
        const u16* pb = wbF + (size_t)rbB*8192 + lane*8;
        #pragma unroll
        for (int f = 0; f < 4; ++f)
            #pragma unroll
            for (int kk = 0; kk < 4; ++kk)
                bfr[f][kk] = *(const bf16x8*)&pb[(kk*4 + f)*512];
    }

    bf16x8 afA[4][4], afB[4][4];
    LOAD_A(afA, 0);
    for (int r = 0; r < 32; r += 2){
        LOAD_A(afB, r+1);
        DO_TILE(afA, r);
        if (r + 2 < 32) LOAD_A(afA, r+2);
        DO_TILE(afB, r+1);
    }
}

// lse[row] = log( sum over 500 partial-chunk sums )   (max-free: logits bounded)
__global__ __launch_bounds__(256) void klse(const float* __restrict__ psum,
                                            float* __restrict__ lse){
    int row = blockIdx.x*256 + threadIdx.x;   // 0..8191
    float S = 0.f;
    for (int cc = 0; cc < NCHUNK; ++cc) S += psum[(size_t)cc*NR + row];
    lse[row] = __logf(S);
}

extern "C" void kernel_launch(void* const* d_in, const int* in_sizes, int n_in,
                              void* d_out, int out_size, void* d_ws, size_t ws_size,
                              hipStream_t stream){
    (void)in_sizes; (void)n_in; (void)out_size; (void)ws_size;
    const int*   seq    = (const int*)d_in[0];
    // d_in[1] encoder_output: unused by the reference
    const float* h0     = (const float*)d_in[2];
    const float* c0     = (const float*)d_in[3];
    const float* emb    = (const float*)d_in[4];
    const float* W_ih   = (const float*)d_in[5];
    const float* b_ih   = (const float*)d_in[6];
    const float* W_hh   = (const float*)d_in[7];
    const float* b_hh   = (const float*)d_in[8];
    const float* W_pred = (const float*)d_in[9];
    const float* b_pred = (const float*)d_in[10];
    float* out = (float*)d_out;

    // Workspace layout. psum (16,384,000 B) ALIASES xg (dead after klstm).
    char* ws = (char*)d_ws;
    float* xg   = (float*)(ws);               // 16,777,216 B  [0 .. 16.78M)
    float* psum = (float*)(ws);               // 16,384,000 B  (alias xg)
    float* hh   = (float*)(ws + 16777216);    //     65,536 B
    u16*   hsb  = (u16*)  (ws + 16842752);    //  2,097,152 B  (row-major)
    u16*   wbbF = (u16*)  (ws + 18939904);    //  8,192,000 B  (F layout)
    float* lse  = (float*)(ws + 27131904);    //     32,768 B
    u16*   hsbF = (u16*)  (ws + 27164672);    //  2,097,152 B  (F layout)

    khh<<<64, 256, 0, stream>>>(h0, W_hh, b_ih, b_hh, hh);
    kwb<<<2000, 256, 0, stream>>>(W_pred, wbbF);
    kxg<<<512, 256, 0, stream>>>(seq, emb, W_ih, xg);
    klstm<<<32, 256, 0, stream>>>(xg, hh, W_ih, c0, hsb);
    ktr<<<1024, 256, 0, stream>>>(hsb, hsbF);
    kgemm<0><<<500, 256, 0, stream>>>(hsbF, wbbF, b_pred, nullptr, psum, out);
    klse<<<32, 256, 0, stream>>>(psum, lse);
    kgemm<1><<<500, 256, 0, stream>>>(hsbF, wbbF, b_pred, lse, psum, out);
}

// Round 16
// 549.704 us; speedup vs baseline: 6.1327x; 1.0168x over previous
//
#include <hip/hip_runtime.h>

typedef short bf16x8 __attribute__((ext_vector_type(8)));
typedef float f32x4  __attribute__((ext_vector_type(4)));
typedef unsigned short u16;
typedef unsigned short u16x8 __attribute__((ext_vector_type(8)));

#define NB   32
#define NS   256
#define NV   32000
#define NE   128
#define NH   128
#define NR   8192   // NB*NS
#define NG   512    // 4*NH
#define NCHUNK 500  // 250 col chunks x 2 wave halves

__device__ __forceinline__ float sigm(float x){
    return __builtin_amdgcn_rcpf(1.0f + __expf(-x));
}
__device__ __forceinline__ float tanh_fast(float x){
    return 1.0f - 2.0f*__builtin_amdgcn_rcpf(1.0f + __expf(2.0f*x));
}

__device__ __forceinline__ u16 f2bf(float x){
    unsigned u = __float_as_uint(x);
    unsigned r = (u + 0x7FFFu + ((u >> 16) & 1u)) >> 16;
    return (u16)r;
}

// raw barrier: waits only LDS ops, lets global loads/stores stay in flight
__device__ __forceinline__ void lds_barrier(){
    asm volatile("s_waitcnt lgkmcnt(0)" ::: "memory");
    __builtin_amdgcn_s_barrier();
    __builtin_amdgcn_sched_barrier(0);
}

// ---------------------------------------------------------------------------
// Fragment-major (F) layout for a [R][128] bf16 matrix, shared by A and B:
//   row m = rb*64 + q*16 + l15,  col j = kk*32 + l4*8 + e,  lane = l4*16+l15
//   F-addr = rb*8192 + (kk*4+q)*512 + lane*8 + e      (u16 units)
// A wave's fragment load reads 64 consecutive 16B chunks per instruction
// (1KB, perfectly coalesced), single base + const offsets.
// ---------------------------------------------------------------------------

// hh[b][j] = b_ih[j] + b_hh[j] + dot(h0[b,:], W_hh[j,:])
__global__ __launch_bounds__(256) void khh(const float* __restrict__ h0,
                                           const float* __restrict__ W_hh,
                                           const float* __restrict__ b_ih,
                                           const float* __restrict__ b_hh,
                                           float* __restrict__ hh){
    int idx = blockIdx.x*256 + threadIdx.x;      // 0..16383
    int b = idx >> 9, j = idx & 511;
    const float4* h4 = (const float4*)(h0 + b*NH);
    const float4* w4 = (const float4*)(W_hh + j*NH);
    float acc = b_ih[j] + b_hh[j];
    #pragma unroll
    for (int k = 0; k < 32; ++k){
        float4 a = h4[k], w = w4[k];
        acc += a.x*w.x + a.y*w.y + a.z*w.z + a.w*w.w;
    }
    hh[idx] = acc;
}

// W_pred fp32 -> bf16, written directly in F layout
__global__ __launch_bounds__(256) void kwb(const float* __restrict__ src, u16* __restrict__ dst){
    int a8 = blockIdx.x*256 + threadIdx.x;    // 512000 16B-chunks
    int a = a8 * 8;
    int rb = a >> 13; int blk = (a >> 9) & 15; int lane = (a >> 3) & 63;
    int q = blk & 3, kk = blk >> 2;
    int l15 = lane & 15, l4 = lane >> 4;
    int m = rb*64 + q*16 + l15;
    int j = kk*32 + l4*8;
    const float* s = src + (size_t)m*NH + j;
    float4 x = *(const float4*)s, y = *(const float4*)(s + 4);
    u16x8 o;
    o[0]=f2bf(x.x); o[1]=f2bf(x.y); o[2]=f2bf(x.z); o[3]=f2bf(x.w);
    o[4]=f2bf(y.x); o[5]=f2bf(y.y); o[6]=f2bf(y.z); o[7]=f2bf(y.w);
    *(u16x8*)&dst[a] = o;
}

// hsb (row-major [8192][128] bf16) -> hsbF (F layout). 2 MB, L2-resident.
__global__ __launch_bounds__(256) void ktr(const u16* __restrict__ src, u16* __restrict__ dst){
    int a8 = blockIdx.x*256 + threadIdx.x;    // 262144 16B-chunks
    int a = a8 * 8;
    int rb = a >> 13; int blk = (a >> 9) & 15; int lane = (a >> 3) & 63;
    int q = blk & 3, kk = blk >> 2;
    int l15 = lane & 15, l4 = lane >> 4;
    int m = rb*64 + q*16 + l15;
    int j = kk*32 + l4*8;
    *(uint4*)&dst[a] = *(const uint4*)&src[(size_t)m*NH + j];
}

// xg[r][j] = dot(emb[seq[r]], W_ih[j][0:128]);  16 rows x 512 cols per block
__global__ __launch_bounds__(256) void kxg(const int* __restrict__ seq,
                                           const float* __restrict__ emb,
                                           const float* __restrict__ W_ih,
                                           float* __restrict__ xg){
    __shared__ float4 xs[16][32];
    int m0 = blockIdx.x * 16;
    int t = threadIdx.x;
    int r = t >> 4, k4 = t & 15;
    int tok = seq[m0 + r];
    xs[r][k4]      = *(const float4*)(emb + (size_t)tok*NE + k4*4);
    xs[r][k4 + 16] = *(const float4*)(emb + (size_t)tok*NE + (k4+16)*4);
    __syncthreads();
    int j0 = t, j1 = t + 256;
    const float4* w0 = (const float4*)(W_ih + (size_t)j0*256);
    const float4* w1 = (const float4*)(W_ih + (size_t)j1*256);
    float acc0[16], acc1[16];
    #pragma unroll
    for (int r2 = 0; r2 < 16; ++r2){ acc0[r2]=0.f; acc1[r2]=0.f; }
    #pragma unroll
    for (int k = 0; k < 32; ++k){
        float4 wa = w0[k], wb = w1[k];
        #pragma unroll
        for (int r2 = 0; r2 < 16; ++r2){
            float4 xv = xs[r2][k];
            acc0[r2] += xv.x*wa.x + xv.y*wa.y + xv.z*wa.z + xv.w*wa.w;
            acc1[r2] += xv.x*wb.x + xv.y*wb.y + xv.z*wb.z + xv.w*wb.w;
        }
    }
    #pragma unroll
    for (int r2 = 0; r2 < 16; ++r2){
        xg[(size_t)(m0+r2)*NG + j0] = acc0[r2];
        xg[(size_t)(m0+r2)*NG + j1] = acc1[r2];
    }
}

// Sequential LSTM, one block/batch, 256 threads, 2 gates/thread, (256,1),
// 4-step x-prefetch with named registers.
#define LSTM_STEP(S, XA, XB) {                                                  \
    float a0=0.f,a1=0.f,a2=0.f,a3=0.f,b0=0.f,b1=0.f,b2=0.f,b3=0.f;              \
    const uint4* h4 = (const uint4*)&hsh2[(S) & 1][0];                          \
    _Pragma("unroll")                                                           \
    for (int k = 0; k < 16; ++k){                                               \
        uint4 hv = h4[k];                                                       \
        asm("v_dot2_f32_bf16 %0, %1, %2, %0" : "+v"(a0) : "v"(hv.x), "v"(w2a[4*k+0])); \
        asm("v_dot2_f32_bf16 %0, %1, %2, %0" : "+v"(a1) : "v"(hv.y), "v"(w2a[4*k+1])); \
        asm("v_dot2_f32_bf16 %0, %1, %2, %0" : "+v"(a2) : "v"(hv.z), "v"(w2a[4*k+2])); \
        asm("v_dot2_f32_bf16 %0, %1, %2, %0" : "+v"(a3) : "v"(hv.w), "v"(w2a[4*k+3])); \
        asm("v_dot2_f32_bf16 %0, %1, %2, %0" : "+v"(b0) : "v"(hv.x), "v"(w2b[4*k+0])); \
        asm("v_dot2_f32_bf16 %0, %1, %2, %0" : "+v"(b1) : "v"(hv.y), "v"(w2b[4*k+1])); \
        asm("v_dot2_f32_bf16 %0, %1, %2, %0" : "+v"(b2) : "v"(hv.z), "v"(w2b[4*k+2])); \
        asm("v_dot2_f32_bf16 %0, %1, %2, %0" : "+v"(b3) : "v"(hv.w), "v"(w2b[4*k+3])); \
    }                                                                           \
    float gateA = hba + (XA) + ((a0+a1)+(a2+a3));                               \
    float gateB = hbb + (XB) + ((b0+b1)+(b2+b3));                               \
    float fg = __shfl_xor(gateA, 1);                                            \
    float og = __shfl_xor(gateB, 1);                                            \
    float cc = sigm(fg)*c0r + sigm(gateA)*tanh_fast(gateB);                     \
    float h  = sigm(og)*tanh_fast(cc);                                          \
    u16 hb16 = f2bf(h);                                                         \
    if (!odd) hrow[(S)*NH + r] = hb16;                                          \
    unsigned hpart = __shfl_xor((unsigned)hb16, 2);                             \
    if ((t & 3) == 0) hsh2[((S) & 1) ^ 1][r >> 1] = (hpart << 16) | (unsigned)hb16; \
    lds_barrier();                                                              \
}

__global__ __launch_bounds__(256, 1) void klstm(const float* __restrict__ xg,
                                                const float* __restrict__ hh,
                                                const float* __restrict__ W_ih,
                                                const float* __restrict__ c0,
                                                u16* __restrict__ hs){
    __shared__ __align__(16) unsigned hsh2[2][64];   // h as 64 packed bf16 pairs, x2 buffers
    int b = blockIdx.x, t = threadIdx.x;
    int r = t >> 1, odd = t & 1;
    int gA = r + (odd ? 128 : 0);        // i-gate row (even) / f-gate row (odd)
    int gB = gA + 256;                   // g-gate row (even) / o-gate row (odd)
    unsigned w2a[64], w2b[64];
    const float2* wra = (const float2*)(W_ih + (size_t)gA*256 + 128);
    const float2* wrb = (const float2*)(W_ih + (size_t)gB*256 + 128);
    #pragma unroll
    for (int k = 0; k < 64; ++k){
        float2 va = wra[k], vb = wrb[k];
        w2a[k] = ((unsigned)f2bf(va.y) << 16) | (unsigned)f2bf(va.x);
        w2b[k] = ((unsigned)f2bf(vb.y) << 16) | (unsigned)f2bf(vb.x);
    }
    float hba = hh[b*NG + gA];
    float hbb = hh[b*NG + gB];
    float c0r = c0[b*NH + r];
    if (t < 64){ hsh2[0][t] = 0u; }      // h_init = 0
    __syncthreads();
    const float* xrow = xg + (size_t)b*NS*NG;
    u16* hrow = hs + (size_t)b*NS*NH;
    float x0a = xrow[gA],        x0b = xrow[gB];
    float x1a = xrow[NG+gA],     x1b = xrow[NG+gB];
    float x2a = xrow[2*NG+gA],   x2b = xrow[2*NG+gB];
    float x3a = xrow[3*NG+gA],   x3b = xrow[3*NG+gB];
    for (int s4 = 0; s4 < NS; s4 += 4){
        float n0a=0.f,n0b=0.f,n1a=0.f,n1b=0.f,n2a=0.f,n2b=0.f,n3a=0.f,n3b=0.f;
        if (s4 + 4 < NS){
            const float* xn = xrow + (size_t)(s4+4)*NG;
            n0a = xn[gA];      n0b = xn[gB];
            n1a = xn[NG+gA];   n1b = xn[NG+gB];
            n2a = xn[2*NG+gA]; n2b = xn[2*NG+gB];
            n3a = xn[3*NG+gA]; n3b = xn[3*NG+gB];
        }
        LSTM_STEP(s4+0, x0a, x0b);
        LSTM_STEP(s4+1, x1a, x1b);
        LSTM_STEP(s4+2, x2a, x2b);
        LSTM_STEP(s4+3, x3a, x3b);
        x0a=n0a; x0b=n0b; x1a=n1a; x1b=n1b;
        x2a=n2a; x2b=n2b; x3a=n3a; x3b=n3b;
    }
}

// ---------------------------------------------------------------------------
// Barrier-free, LDS-free MFMA GEMM, coalesced F-layout fragment loads.
// R15 audit: afA+afB double-buffer put live VGPRs at ~290 > the 256 cap from
// (256,2) -> spills. Fix: SINGLE af buffer, reloaded for tile r+1 between
// the MFMA block and the epilogue — the exp/store epilogue (~150-300cyc)
// hides the L2 load latency; live set ~215 VGPR, no spill, same overlap.
// PASS 0: psum[(c*2+wc)][row] = sum_j exp(logit)  (coalesced per-wave store;
//         only bpl4 = bias*log2e kept in regs).
// PASS 1: out = logit - lse[row]  (only bp4 kept).
// ---------------------------------------------------------------------------

#define LOAD_A(DST, R) {                                                        \
    int rbA = (mbase >> 6) + (R)*2 + wr;                                        \
    const u16* pa = hsbF + (size_t)rbA*8192 + lane*8;                           \
    _Pragma("unroll")                                                           \
    for (int q = 0; q < 4; ++q)                                                 \
        _Pragma("unroll")                                                       \
        for (int kk = 0; kk < 4; ++kk)                                          \
            DST[q][kk] = *(const bf16x8*)&pa[(kk*4 + q)*512];                   \
}

template<int PASS>
__global__ __launch_bounds__(256, 2) void kgemm(const u16* __restrict__ hsbF,
                                                const u16* __restrict__ wbF,
                                                const float* __restrict__ bpred,
                                                const float* __restrict__ lse,
                                                float* __restrict__ psum,
                                                float* __restrict__ out){
    int tid = threadIdx.x;
    int bid = blockIdx.x;
    int c    = bid >> 1;                  // col chunk 0..249
    int half = bid & 1;                   // row half
    int n0 = c * 128;
    int mbase = half * 4096;

    int wid = tid >> 6, lane = tid & 63;
    int wr = wid >> 1, wc = wid & 1;      // 2 row-groups x 2 col-groups of 64
    int l15 = lane & 15, l4 = lane >> 4;
    const float L2E = 1.44269504f;
    float4 bp4[4];                        // pass1: bias; pass0: bias*log2e
    #pragma unroll
    for (int f = 0; f < 4; ++f){
        bp4[f] = *(const float4*)&bpred[n0 + wc*64 + f*16 + l4*4];
        if (PASS == 0){
            bp4[f].x *= L2E; bp4[f].y *= L2E; bp4[f].z *= L2E; bp4[f].w *= L2E;
        }
    }

    // B fragments: this wave's 64x128 W chunk, in regs, coalesced F reads.
    bf16x8 bfr[4][4];
    {
        int rbB = c*2 + wc;
        const u16* pb = wbF + (size_t)rbB*8192 + lane*8;
        #pragma unroll
        for (int f = 0; f < 4; ++f)
            #pragma unroll
            for (int kk = 0; kk < 4; ++kk)
                bfr[f][kk] = *(const bf16x8*)&pb[(kk*4 + f)*512];
    }

    bf16x8 af[4][4];
    LOAD_A(af, 0);
    for (int r = 0; r < 32; ++r){
        f32x4 acc[4][4];
        #pragma unroll
        for (int q = 0; q < 4; ++q)
            #pragma unroll
            for (int f = 0; f < 4; ++f)
                acc[q][f] = (f32x4){0.f,0.f,0.f,0.f};
        #pragma unroll
        for (int f = 0; f < 4; ++f)
            #pragma unroll
            for (int q = 0; q < 4; ++q)
                #pragma unroll
                for (int kk = 0; kk < 4; ++kk)
                    acc[q][f] = __builtin_amdgcn_mfma_f32_16x16x32_bf16(
                        bfr[f][kk], af[q][kk], acc[q][f], 0, 0, 0);

        // af is dead now — reload same regs for r+1; the epilogue below
        // overlaps the load latency.
        if (r + 1 < 32) LOAD_A(af, r+1);

        if (PASS == 0){
            float lsum[4];
            #pragma unroll
            for (int q = 0; q < 4; ++q){
                float s = 0.f;
                #pragma unroll
                for (int f = 0; f < 4; ++f)
                    #pragma unroll
                    for (int rr = 0; rr < 4; ++rr){
                        float tt = fmaf(acc[q][f][rr], L2E, bp4[f][rr]);
                        float e; asm("v_exp_f32 %0, %1" : "=v"(e) : "v"(tt));
                        s += e;
                    }
                s += __shfl_xor(s, 16);
                s += __shfl_xor(s, 32);
                lsum[q] = s;
            }
            float sv = (l4 == 0) ? lsum[0] : (l4 == 1) ? lsum[1]
                     : (l4 == 2) ? lsum[2] : lsum[3];
            psum[(size_t)(c*2 + wc)*NR + mbase + r*128 + wr*64 + lane] = sv;
        } else {
            #pragma unroll
            for (int q = 0; q < 4; ++q){
                int grow = mbase + r*128 + wr*64 + q*16 + l15;
                float lw = lse[grow];
                float* orow = out + (size_t)grow*NV + n0 + wc*64 + l4*4;
                #pragma unroll
                for (int f = 0; f < 4; ++f){
                    f32x4 v;
                    v[0] = acc[q][f][0] + bp4[f].x - lw;
                    v[1] = acc[q][f][1] + bp4[f].y - lw;
                    v[2] = acc[q][f][2] + bp4[f].z - lw;
                    v[3] = acc[q][f][3] + bp4[f].w - lw;
                    *(f32x4*)&orow[f*16] = v;
                }
            }
        }
    }
}

// lse[row] = log( sum over 500 partial-chunk sums ).  256 blocks x 32 rows,
// 8-way chunk split per row + LDS reduce (was 32 blocks = 1/8 CU occupancy).
__global__ __launch_bounds__(256) void klse(const float* __restrict__ psum,
                                            float* __restrict__ lse){
    __shared__ float red[32][8];
    int t = threadIdx.x;
    int row = blockIdx.x*32 + (t >> 3);   // 0..8191
    int grp = t & 7;
    float S = 0.f;
    for (int cc = grp; cc < NCHUNK; cc += 8)
        S += psum[(size_t)cc*NR + row];
    red[t >> 3][grp] = S;
    __syncthreads();
    if (grp == 0){
        float s2 = 0.f;
        #pragma unroll
        for (int g = 0; g < 8; ++g) s2 += red[t >> 3][g];
        lse[row] = __logf(s2);
    }
}

extern "C" void kernel_launch(void* const* d_in, const int* in_sizes, int n_in,
                              void* d_out, int out_size, void* d_ws, size_t ws_size,
                              hipStream_t stream){
    (void)in_sizes; (void)n_in; (void)out_size; (void)ws_size;
    const int*   seq    = (const int*)d_in[0];
    // d_in[1] encoder_output: unused by the reference
    const float* h0     = (const float*)d_in[2];
    const float* c0     = (const float*)d_in[3];
    const float* emb    = (const float*)d_in[4];
    const float* W_ih   = (const float*)d_in[5];
    const float* b_ih   = (const float*)d_in[6];
    const float* W_hh   = (const float*)d_in[7];
    const float* b_hh   = (const float*)d_in[8];
    const float* W_pred = (const float*)d_in[9];
    const float* b_pred = (const float*)d_in[10];
    float* out = (float*)d_out;

    // Workspace layout. psum (16,384,000 B) ALIASES xg (dead after klstm).
    char* ws = (char*)d_ws;
    float* xg   = (float*)(ws);               // 16,777,216 B  [0 .. 16.78M)
    float* psum = (float*)(ws);               // 16,384,000 B  (alias xg)
    float* hh   = (float*)(ws + 16777216);    //     65,536 B
    u16*   hsb  = (u16*)  (ws + 16842752);    //  2,097,152 B  (row-major)
    u16*   wbbF = (u16*)  (ws + 18939904);    //  8,192,000 B  (F layout)
    float* lse  = (float*)(ws + 27131904);    //     32,768 B
    u16*   hsbF = (u16*)  (ws + 27164672);    //  2,097,152 B  (F layout)

    khh<<<64, 256, 0, stream>>>(h0, W_hh, b_ih, b_hh, hh);
    kwb<<<2000, 256, 0, stream>>>(W_pred, wbbF);
    kxg<<<512, 256, 0, stream>>>(seq, emb, W_ih, xg);
    klstm<<<32, 256, 0, stream>>>(xg, hh, W_ih, c0, hsb);
    ktr<<<1024, 256, 0, stream>>>(hsb, hsbF);
    kgemm<0><<<500, 256, 0, stream>>>(hsbF, wbbF, b_pred, nullptr, psum, out);
    klse<<<256, 256, 0, stream>>>(psum, lse);
    kgemm<1><<<500, 256, 0, stream>>>(hsbF, wbbF, b_pred, lse, psum, out);
}